// Round 9
// baseline (306.285 us; speedup 1.0000x reference)
//
#include <hip/hip_runtime.h>
#include <cstdint>
#include <cstddef>

typedef __attribute__((ext_vector_type(8))) short short8;
typedef __attribute__((ext_vector_type(16))) float floatx16;

__device__ __forceinline__ unsigned short f2bf(float f) {
    union { float f; unsigned int u; } v; v.f = f;
    unsigned int r = v.u + 0x7fffu + ((v.u >> 16) & 1u);
    return (unsigned short)(r >> 16);
}

__device__ __forceinline__ void glds16(const void* g, void* l) {
    __builtin_amdgcn_global_load_lds(
        (const __attribute__((address_space(1))) void*)g,
        (__attribute__((address_space(3))) void*)l, 16, 0, 0);
}

// C/D layout (m74/m101, verified): col = lane&31, row = (r&3)+8*(r>>2)+4*kg
#define EPI_ROW(r, kg) (((r) & 3) + 8 * ((r) >> 2) + 4 * (kg))

// ============ 128x128 core, 2-barrier loop (measured ~1000 TF true @ 4 blk/CU)
// Swizzle (verified: SQ_LDS_BANK_CONFLICT == 0): key(row)=(row^(row>>3))&7
__device__ __forceinline__ void gemm_core(
    const unsigned short* __restrict__ Ab, int ldA,
    const unsigned short* __restrict__ Bb, int ldB,
    int K,
    unsigned short* __restrict__ As, unsigned short* __restrict__ Bs,
    floatx16 (&acc)[2][2])
{
    const int tid = threadIdx.x;
    const int wave = tid >> 6, lane = tid & 63;

    const unsigned short* gA[4];
    const unsigned short* gB[4];
#pragma unroll
    for (int i = 0; i < 4; ++i) {
        const int c = i * 256 + tid;
        const int row = c >> 3;
        const int l = (c & 7) ^ ((row ^ (row >> 3)) & 7);
        gA[i] = Ab + (size_t)row * ldA + l * 8;
        gB[i] = Bb + (size_t)row * ldB + l * 8;
    }
    const int arow = (wave >> 1) * 64 + (lane & 31);
    const int brow = (wave & 1) * 64 + (lane & 31);
    const int kg = lane >> 5;
    const int sw = (lane & 7) ^ ((lane >> 3) & 3);
    const unsigned short* pa = As + arow * 64;
    const unsigned short* pb = Bs + brow * 64;

    for (int k0 = 0; k0 < K; k0 += 64) {
#pragma unroll
        for (int i = 0; i < 4; ++i)
            glds16(gA[i] + k0, As + (size_t)(i * 256 + wave * 64) * 8);
#pragma unroll
        for (int i = 0; i < 4; ++i)
            glds16(gB[i] + k0, Bs + (size_t)(i * 256 + wave * 64) * 8);
        __syncthreads();
#pragma unroll
        for (int s = 0; s < 4; ++s) {
            const int o0 = ((2 * s + kg) ^ sw) * 8;
            const int o1 = o0 ^ 32;
            short8 a0 = *(const short8*)(pa + o0);
            short8 a1 = *(const short8*)(pa + 32 * 64 + o1);
            short8 b0 = *(const short8*)(pb + o0);
            short8 b1 = *(const short8*)(pb + 32 * 64 + o1);
            acc[0][0] = __builtin_amdgcn_mfma_f32_32x32x16_bf16(a0, b0, acc[0][0], 0, 0, 0);
            acc[0][1] = __builtin_amdgcn_mfma_f32_32x32x16_bf16(a0, b1, acc[0][1], 0, 0, 0);
            acc[1][0] = __builtin_amdgcn_mfma_f32_32x32x16_bf16(a1, b0, acc[1][0], 0, 0, 0);
            acc[1][1] = __builtin_amdgcn_mfma_f32_32x32x16_bf16(a1, b1, acc[1][1], 0, 0, 0);
        }
        __syncthreads();
    }
}

// ====== prep: fp32->bf16 converts + weight transpose-converts + lrow zero ====
__global__ __launch_bounds__(256) void prep_kernel(
    const float* __restrict__ x, const float* __restrict__ ctx,
    const float* __restrict__ Wq, const float* __restrict__ Wk, const float* __restrict__ Wv,
    unsigned short* __restrict__ xb, unsigned short* __restrict__ cb,
    unsigned short* __restrict__ Wt0, unsigned short* __restrict__ WtKV,
    float* __restrict__ lrow) {
    const int b = blockIdx.x;
    if (b < 16384) {
        int i = b * 256 + threadIdx.x;
        const float* in; unsigned short* out; int j;
        if (i < 2097152) { in = x; out = xb; j = i; }
        else { in = ctx; out = cb; j = i - 2097152; }
        float4 v = reinterpret_cast<const float4*>(in)[j];
        ushort4 o;
        o.x = f2bf(v.x); o.y = f2bf(v.y); o.z = f2bf(v.z); o.w = f2bf(v.w);
        reinterpret_cast<ushort4*>(out)[j] = o;
    } else if (b < 19456) {
        // weight transpose, widened: float4 loads, ushort4 stores
        __shared__ float tile[32][33];
        const int z = b - 16384;
        const int w = z >> 10, t = z & 1023;
        const float* in = (w == 0) ? Wq : (w == 1) ? Wk : Wv;
        unsigned short* out = (w == 0) ? Wt0 : (w == 1) ? WtKV : (WtKV + 1024 * 1024);
        const int c0 = (t & 31) * 32, r0 = (t >> 5) * 32;
        const int tq = threadIdx.x & 7, tr = threadIdx.x >> 3;   // 8 x 32
        float4 v = *reinterpret_cast<const float4*>(&in[(size_t)(r0 + tr) * 1024 + c0 + tq * 4]);
        tile[tr][tq * 4 + 0] = v.x; tile[tr][tq * 4 + 1] = v.y;
        tile[tr][tq * 4 + 2] = v.z; tile[tr][tq * 4 + 3] = v.w;
        __syncthreads();
        ushort4 u;
        u.x = f2bf(tile[tq * 4 + 0][tr]);
        u.y = f2bf(tile[tq * 4 + 1][tr]);
        u.z = f2bf(tile[tq * 4 + 2][tr]);
        u.w = f2bf(tile[tq * 4 + 3][tr]);
        *reinterpret_cast<ushort4*>(&out[(size_t)(c0 + tr) * 1024 + r0 + tq * 4]) = u;
    } else {
        // zero lrow: 8192 floats = 2048 float4 over 8 blocks x 256 threads
        const int i = (b - 19456) * 256 + threadIdx.x;
        reinterpret_cast<float4*>(lrow)[i] = float4{0.f, 0.f, 0.f, 0.f};
    }
}

// ===== mega QKV: 768 persistent-lite blocks x 2 tiles (1536 tiles total) =====
// 768 = exactly 3 blocks/CU, all co-resident -> no half-empty second wave
// (1536 blocks @4/CU capacity 1024 ran as 1024 + 512-tail; ~8-15 us wasted).
// Both tiles of a block are in the same %8 class (768%8==0) -> XCD
// co-location (i%8==by%8) preserved for A-panel L2 sharing.
__global__ __launch_bounds__(256, 4) void qkv_kernel(
    const unsigned short* __restrict__ xb, const unsigned short* __restrict__ cb,
    const unsigned short* __restrict__ WtQ, const unsigned short* __restrict__ WtKV,
    const float* __restrict__ bq, const float* __restrict__ bk, const float* __restrict__ bv,
    unsigned short* __restrict__ Qb, unsigned short* __restrict__ Kb,
    unsigned short* __restrict__ Vt) {
    __shared__ unsigned short As[128 * 64];
    __shared__ unsigned short Bs[128 * 64];
    for (int t = 0; t < 2; ++t) {
        const int i = (int)blockIdx.x + t * 768;
        const bool isQ = i < 512;
        int by, bxcol;
        const unsigned short *A, *B;
        if (isQ) {
            const int slot = i >> 3;
            by = (i & 7) + 8 * (slot & 7);
            const int bx = slot >> 3; bxcol = bx * 128;
            A = xb + (size_t)by * 128 * 1024;
            B = WtQ + (size_t)bx * 128 * 1024;
        } else {
            const int j = i - 512;
            const int slot = j >> 3;
            by = (j & 7) + 8 * (slot & 7);
            const int bx = slot >> 3; bxcol = bx * 128;
            A = cb + (size_t)by * 128 * 1024;
            B = WtKV + (size_t)bx * 128 * 1024;
        }
        floatx16 acc[2][2];
#pragma unroll
        for (int a = 0; a < 2; ++a)
#pragma unroll
            for (int bj = 0; bj < 2; ++bj)
#pragma unroll
                for (int r = 0; r < 16; ++r) acc[a][bj][r] = 0.f;

        gemm_core(A, 1024, B, 1024, 1024, As, Bs, acc);

        const int wave = threadIdx.x >> 6, lane = threadIdx.x & 63;
        const int kg = lane >> 5;
        const int cm = by * 128 + (wave >> 1) * 64;
        const int cn = bxcol + (wave & 1) * 64 + (lane & 31);
        if (isQ || bxcol < 1024) {
            unsigned short* O = isQ ? Qb : Kb;
            const float* bias = isQ ? bq : bk;
#pragma unroll
            for (int nt = 0; nt < 2; ++nt) {
                const int col = cn + nt * 32;
                const float bvv = bias[col];
#pragma unroll
                for (int mt = 0; mt < 2; ++mt)
#pragma unroll
                    for (int r = 0; r < 16; ++r) {
                        const int row = cm + mt * 32 + EPI_ROW(r, kg);
                        O[(size_t)row * 1024 + col] = f2bf(acc[mt][nt][r] + bvv);
                    }
            }
        } else {
            // V half -> transposed write: Vt[b][colv][q]; 4 consecutive q/quad
#pragma unroll
            for (int nt = 0; nt < 2; ++nt) {
                const int colv = cn + nt * 32 - 1024;
                const float bvv = bv[colv];
#pragma unroll
                for (int mt = 0; mt < 2; ++mt) {
                    const int rowg = cm + mt * 32 + 4 * kg;
                    const int b = rowg >> 11, qb = rowg & 2047;
#pragma unroll
                    for (int g = 0; g < 4; ++g) {
                        const int q = qb + 8 * g;
                        ushort4 u;
                        u.x = f2bf(acc[mt][nt][g * 4 + 0] + bvv);
                        u.y = f2bf(acc[mt][nt][g * 4 + 1] + bvv);
                        u.z = f2bf(acc[mt][nt][g * 4 + 2] + bvv);
                        u.w = f2bf(acc[mt][nt][g * 4 + 3] + bvv);
                        *reinterpret_cast<ushort4*>(Vt + (size_t)b * 2097152 + (size_t)colv * 2048 + q) = u;
                    }
                }
            }
        }
    }
}

// ============ P_unnorm = exp(Q K^T * scale); row sums -> l via atomics ========
// 1024 blocks = exactly one 4-blk/CU wave (perfectly packed; R6-verified)
__global__ __launch_bounds__(256, 4) void qkt_kernel(
    const unsigned short* __restrict__ Qb, const unsigned short* __restrict__ Kb,
    unsigned short* __restrict__ Sb, float* __restrict__ l) {
    __shared__ unsigned short As[128 * 64];
    __shared__ unsigned short Bs[128 * 64];
    const int i = blockIdx.x;                    // 0..1023
    const int z = (i >> 1) & 3;
    const int slot = i >> 3;
    const int by = (i & 1) + 2 * (slot & 7);
    const int bx = slot >> 3;
    const unsigned short* A = Qb + (size_t)z * 2097152 + (size_t)by * 128 * 1024;
    const unsigned short* B = Kb + (size_t)z * 2097152 + (size_t)bx * 128 * 1024;
    floatx16 acc[2][2];
#pragma unroll
    for (int a = 0; a < 2; ++a)
#pragma unroll
        for (int bj = 0; bj < 2; ++bj)
#pragma unroll
            for (int r = 0; r < 16; ++r) acc[a][bj][r] = 0.f;

    gemm_core(A, 1024, B, 1024, 1024, As, Bs, acc);

    const int wave = threadIdx.x >> 6, lane = threadIdx.x & 63;
    const int kg = lane >> 5;
    unsigned short* C = Sb + (size_t)z * 4194304;
    float* lz = l + z * 2048;
    const int cm = by * 128 + (wave >> 1) * 64;
    const int cn = bx * 128 + (wave & 1) * 64 + (lane & 31);
#pragma unroll
    for (int mt = 0; mt < 2; ++mt)
#pragma unroll
        for (int r = 0; r < 16; ++r) {
            const int row = cm + mt * 32 + EPI_ROW(r, kg);
            const float e0 = __expf(acc[mt][0][r] * 0.03125f);
            const float e1 = __expf(acc[mt][1][r] * 0.03125f);
            C[(size_t)row * 2048 + cn] = f2bf(e0);
            C[(size_t)row * 2048 + cn + 32] = f2bf(e1);
            float s = e0 + e1;
            s += __shfl_xor(s, 1);  s += __shfl_xor(s, 2);
            s += __shfl_xor(s, 4);  s += __shfl_xor(s, 8);
            s += __shfl_xor(s, 16);
            if ((lane & 31) == (mt * 16 + r)) atomicAdd(&lz[row], s);
        }
}

// ============ out = (P_unnorm @ Vt^T) / l[row] (fp32 out) ============
// (R6-verified body; 512 blocks = one 2-blk/CU wave)
__global__ __launch_bounds__(256, 4) void pv_kernel(
    const unsigned short* __restrict__ Sb, const unsigned short* __restrict__ Vt,
    const float* __restrict__ l, float* __restrict__ out) {
    __shared__ unsigned short As[128 * 64];
    __shared__ unsigned short Bs[128 * 64];
    const int i = blockIdx.x;                    // 0..511
    const int z = (i >> 1) & 3;
    const int slot = i >> 3;
    const int by = (i & 1) + 2 * (slot & 7);
    const int bx = slot >> 3;
    const unsigned short* A = Sb + (size_t)z * 4194304 + (size_t)by * 128 * 2048;
    const unsigned short* B = Vt + (size_t)z * 2097152 + (size_t)bx * 128 * 2048;
    floatx16 acc[2][2];
#pragma unroll
    for (int a = 0; a < 2; ++a)
#pragma unroll
        for (int bj = 0; bj < 2; ++bj)
#pragma unroll
            for (int r = 0; r < 16; ++r) acc[a][bj][r] = 0.f;

    gemm_core(A, 2048, B, 2048, 2048, As, Bs, acc);

    const int wave = threadIdx.x >> 6, lane = threadIdx.x & 63;
    const int kg = lane >> 5;
    float* C = out + (size_t)z * 2097152;
    const float* lz = l + z * 2048;
    const int cm = by * 128 + (wave >> 1) * 64;
    const int cn = bx * 128 + (wave & 1) * 64 + (lane & 31);
#pragma unroll
    for (int mt = 0; mt < 2; ++mt)
#pragma unroll
        for (int r = 0; r < 16; ++r) {
            const int row = cm + mt * 32 + EPI_ROW(r, kg);
            const float inv = 1.0f / lz[row];
            C[(size_t)row * 1024 + cn] = acc[mt][0][r] * inv;
            C[(size_t)row * 1024 + cn + 32] = acc[mt][1][r] * inv;
        }
}

extern "C" void kernel_launch(void* const* d_in, const int* in_sizes, int n_in,
                              void* d_out, int out_size, void* d_ws, size_t ws_size,
                              hipStream_t stream) {
    const float* x   = (const float*)d_in[0];
    const float* ctx = (const float*)d_in[1];
    const float* Wq  = (const float*)d_in[2];
    const float* bq  = (const float*)d_in[3];
    const float* Wk  = (const float*)d_in[4];
    const float* bk  = (const float*)d_in[5];
    const float* Wv  = (const float*)d_in[6];
    const float* bv  = (const float*)d_in[7];
    float* out = (float*)d_out;

    const size_t MB = 1024 * 1024;
    char* ws = (char*)d_ws;
    unsigned short* xb   = (unsigned short*)(ws + 0 * MB);
    unsigned short* cb   = (unsigned short*)(ws + 16 * MB);
    unsigned short* Qb   = (unsigned short*)(ws + 32 * MB);
    unsigned short* Kb   = (unsigned short*)(ws + 48 * MB);
    unsigned short* Vt   = (unsigned short*)(ws + 64 * MB);
    unsigned short* Wt0  = (unsigned short*)(ws + 80 * MB);
    unsigned short* WtKV = (unsigned short*)(ws + 82 * MB);
    unsigned short* Sb   = (unsigned short*)(ws + 86 * MB);
    float*          lrow = (float*)(ws + 118 * MB);   // 8192 fp32 row sums

    prep_kernel<<<16384 + 3072 + 8, 256, 0, stream>>>(
        x, ctx, Wq, Wk, Wv, xb, cb, Wt0, WtKV, lrow);
    qkv_kernel<<<768, 256, 0, stream>>>(xb, cb, Wt0, WtKV, bq, bk, bv, Qb, Kb, Vt);
    qkt_kernel<<<1024, 256, 0, stream>>>(Qb, Kb, Sb, lrow);
    pv_kernel<<<512, 256, 0, stream>>>(Sb, Vt, lrow, out);
}

// Round 10
// 279.868 us; speedup vs baseline: 1.0944x; 1.0944x over previous
//
#include <hip/hip_runtime.h>
#include <cstdint>
#include <cstddef>

typedef __attribute__((ext_vector_type(8))) short short8;
typedef __attribute__((ext_vector_type(16))) float floatx16;

__device__ __forceinline__ unsigned short f2bf(float f) {
    union { float f; unsigned int u; } v; v.f = f;
    unsigned int r = v.u + 0x7fffu + ((v.u >> 16) & 1u);
    return (unsigned short)(r >> 16);
}

__device__ __forceinline__ void glds16(const void* g, void* l) {
    __builtin_amdgcn_global_load_lds(
        (const __attribute__((address_space(1))) void*)g,
        (__attribute__((address_space(3))) void*)l, 16, 0, 0);
}

// C/D layout (m74/m101, verified): col = lane&31, row = (r&3)+8*(r>>2)+4*kg
#define EPI_ROW(r, kg) (((r) & 3) + 8 * ((r) >> 2) + 4 * (kg))

// ============ 128x128 core, 2-barrier loop (measured 810 TF @ 4 blk/CU) ======
// Swizzle (verified: SQ_LDS_BANK_CONFLICT == 0): key(row)=(row^(row>>3))&7
__device__ __forceinline__ void gemm_core(
    const unsigned short* __restrict__ Ab, int ldA,
    const unsigned short* __restrict__ Bb, int ldB,
    int K,
    unsigned short* __restrict__ As, unsigned short* __restrict__ Bs,
    floatx16 (&acc)[2][2])
{
    const int tid = threadIdx.x;
    const int wave = tid >> 6, lane = tid & 63;

    const unsigned short* gA[4];
    const unsigned short* gB[4];
#pragma unroll
    for (int i = 0; i < 4; ++i) {
        const int c = i * 256 + tid;
        const int row = c >> 3;
        const int l = (c & 7) ^ ((row ^ (row >> 3)) & 7);
        gA[i] = Ab + (size_t)row * ldA + l * 8;
        gB[i] = Bb + (size_t)row * ldB + l * 8;
    }
    const int arow = (wave >> 1) * 64 + (lane & 31);
    const int brow = (wave & 1) * 64 + (lane & 31);
    const int kg = lane >> 5;
    const int sw = (lane & 7) ^ ((lane >> 3) & 3);
    const unsigned short* pa = As + arow * 64;
    const unsigned short* pb = Bs + brow * 64;

    for (int k0 = 0; k0 < K; k0 += 64) {
#pragma unroll
        for (int i = 0; i < 4; ++i)
            glds16(gA[i] + k0, As + (size_t)(i * 256 + wave * 64) * 8);
#pragma unroll
        for (int i = 0; i < 4; ++i)
            glds16(gB[i] + k0, Bs + (size_t)(i * 256 + wave * 64) * 8);
        __syncthreads();
#pragma unroll
        for (int s = 0; s < 4; ++s) {
            const int o0 = ((2 * s + kg) ^ sw) * 8;
            const int o1 = o0 ^ 32;
            short8 a0 = *(const short8*)(pa + o0);
            short8 a1 = *(const short8*)(pa + 32 * 64 + o1);
            short8 b0 = *(const short8*)(pb + o0);
            short8 b1 = *(const short8*)(pb + 32 * 64 + o1);
            acc[0][0] = __builtin_amdgcn_mfma_f32_32x32x16_bf16(a0, b0, acc[0][0], 0, 0, 0);
            acc[0][1] = __builtin_amdgcn_mfma_f32_32x32x16_bf16(a0, b1, acc[0][1], 0, 0, 0);
            acc[1][0] = __builtin_amdgcn_mfma_f32_32x32x16_bf16(a1, b0, acc[1][0], 0, 0, 0);
            acc[1][1] = __builtin_amdgcn_mfma_f32_32x32x16_bf16(a1, b1, acc[1][1], 0, 0, 0);
        }
        __syncthreads();
    }
}

// ====== prep: fp32->bf16 converts + weight transpose-converts + lrow zero ====
__global__ __launch_bounds__(256) void prep_kernel(
    const float* __restrict__ x, const float* __restrict__ ctx,
    const float* __restrict__ Wq, const float* __restrict__ Wk, const float* __restrict__ Wv,
    unsigned short* __restrict__ xb, unsigned short* __restrict__ cb,
    unsigned short* __restrict__ Wt0, unsigned short* __restrict__ WtKV,
    float* __restrict__ lrow) {
    const int b = blockIdx.x;
    if (b < 16384) {
        int i = b * 256 + threadIdx.x;
        const float* in; unsigned short* out; int j;
        if (i < 2097152) { in = x; out = xb; j = i; }
        else { in = ctx; out = cb; j = i - 2097152; }
        float4 v = reinterpret_cast<const float4*>(in)[j];
        ushort4 o;
        o.x = f2bf(v.x); o.y = f2bf(v.y); o.z = f2bf(v.z); o.w = f2bf(v.w);
        reinterpret_cast<ushort4*>(out)[j] = o;
    } else if (b < 19456) {
        // weight transpose, widened: float4 loads, ushort4 stores
        __shared__ float tile[32][33];
        const int z = b - 16384;
        const int w = z >> 10, t = z & 1023;
        const float* in = (w == 0) ? Wq : (w == 1) ? Wk : Wv;
        unsigned short* out = (w == 0) ? Wt0 : (w == 1) ? WtKV : (WtKV + 1024 * 1024);
        const int c0 = (t & 31) * 32, r0 = (t >> 5) * 32;
        const int tq = threadIdx.x & 7, tr = threadIdx.x >> 3;   // 8 x 32
        float4 v = *reinterpret_cast<const float4*>(&in[(size_t)(r0 + tr) * 1024 + c0 + tq * 4]);
        tile[tr][tq * 4 + 0] = v.x; tile[tr][tq * 4 + 1] = v.y;
        tile[tr][tq * 4 + 2] = v.z; tile[tr][tq * 4 + 3] = v.w;
        __syncthreads();
        ushort4 u;
        u.x = f2bf(tile[tq * 4 + 0][tr]);
        u.y = f2bf(tile[tq * 4 + 1][tr]);
        u.z = f2bf(tile[tq * 4 + 2][tr]);
        u.w = f2bf(tile[tq * 4 + 3][tr]);
        *reinterpret_cast<ushort4*>(&out[(size_t)(c0 + tr) * 1024 + r0 + tq * 4]) = u;
    } else {
        // zero lrow: 8192 floats = 2048 float4 over 8 blocks x 256 threads
        const int i = (b - 19456) * 256 + threadIdx.x;
        reinterpret_cast<float4*>(lrow)[i] = float4{0.f, 0.f, 0.f, 0.f};
    }
}

// ============ mega QKV: 1536 blocks of 128x128; Q (512) + KV (1024) ==========
// (R0/R6/R8-verified: ~66 us, MfmaUtil 33-34%, FETCH ~52 MB, XCD co-location.
//  Do NOT restructure: dispatch-order L2 locality is the load-bearing element —
//  persistent 2-tile loop (R9) and stripe-major orders (R7) both blow up FETCH.)
__global__ __launch_bounds__(256, 4) void qkv_kernel(
    const unsigned short* __restrict__ xb, const unsigned short* __restrict__ cb,
    const unsigned short* __restrict__ WtQ, const unsigned short* __restrict__ WtKV,
    const float* __restrict__ bq, const float* __restrict__ bk, const float* __restrict__ bv,
    unsigned short* __restrict__ Qb, unsigned short* __restrict__ Kb,
    unsigned short* __restrict__ Vt) {
    __shared__ unsigned short As[128 * 64];
    __shared__ unsigned short Bs[128 * 64];
    const int i = blockIdx.x;
    const bool isQ = i < 512;
    int by, bxcol;
    const unsigned short *A, *B;
    if (isQ) {
        const int slot = i >> 3;
        by = (i & 7) + 8 * (slot & 7);
        const int bx = slot >> 3; bxcol = bx * 128;
        A = xb + (size_t)by * 128 * 1024;
        B = WtQ + (size_t)bx * 128 * 1024;
    } else {
        const int j = i - 512;
        const int slot = j >> 3;
        by = (j & 7) + 8 * (slot & 7);
        const int bx = slot >> 3; bxcol = bx * 128;
        A = cb + (size_t)by * 128 * 1024;
        B = WtKV + (size_t)bx * 128 * 1024;
    }
    floatx16 acc[2][2];
#pragma unroll
    for (int a = 0; a < 2; ++a)
#pragma unroll
        for (int bj = 0; bj < 2; ++bj)
#pragma unroll
            for (int r = 0; r < 16; ++r) acc[a][bj][r] = 0.f;

    gemm_core(A, 1024, B, 1024, 1024, As, Bs, acc);

    const int wave = threadIdx.x >> 6, lane = threadIdx.x & 63;
    const int kg = lane >> 5;
    const int cm = by * 128 + (wave >> 1) * 64;
    const int cn = bxcol + (wave & 1) * 64 + (lane & 31);
    if (isQ || bxcol < 1024) {
        unsigned short* O = isQ ? Qb : Kb;
        const float* bias = isQ ? bq : bk;
#pragma unroll
        for (int nt = 0; nt < 2; ++nt) {
            const int col = cn + nt * 32;
            const float bvv = bias[col];
#pragma unroll
            for (int mt = 0; mt < 2; ++mt)
#pragma unroll
                for (int r = 0; r < 16; ++r) {
                    const int row = cm + mt * 32 + EPI_ROW(r, kg);
                    O[(size_t)row * 1024 + col] = f2bf(acc[mt][nt][r] + bvv);
                }
        }
    } else {
        // V half -> transposed write: Vt[b][colv][q]; 4 consecutive q per reg-quad
#pragma unroll
        for (int nt = 0; nt < 2; ++nt) {
            const int colv = cn + nt * 32 - 1024;
            const float bvv = bv[colv];
#pragma unroll
            for (int mt = 0; mt < 2; ++mt) {
                const int rowg = cm + mt * 32 + 4 * kg;
                const int b = rowg >> 11, qb = rowg & 2047;
#pragma unroll
                for (int g = 0; g < 4; ++g) {
                    const int q = qb + 8 * g;
                    ushort4 u;
                    u.x = f2bf(acc[mt][nt][g * 4 + 0] + bvv);
                    u.y = f2bf(acc[mt][nt][g * 4 + 1] + bvv);
                    u.z = f2bf(acc[mt][nt][g * 4 + 2] + bvv);
                    u.w = f2bf(acc[mt][nt][g * 4 + 3] + bvv);
                    *reinterpret_cast<ushort4*>(Vt + (size_t)b * 2097152 + (size_t)colv * 2048 + q) = u;
                }
            }
        }
    }
}

// ============ P_unnorm = exp(Q K^T * scale); row sums -> l via atomics ========
// (R0/R6-verified body; logits bounded so no max-subtract needed)
__global__ __launch_bounds__(256, 4) void qkt_kernel(
    const unsigned short* __restrict__ Qb, const unsigned short* __restrict__ Kb,
    unsigned short* __restrict__ Sb, float* __restrict__ l) {
    __shared__ unsigned short As[128 * 64];
    __shared__ unsigned short Bs[128 * 64];
    const int i = blockIdx.x;                    // 0..1023
    const int z = (i >> 1) & 3;
    const int slot = i >> 3;
    const int by = (i & 1) + 2 * (slot & 7);
    const int bx = slot >> 3;
    const unsigned short* A = Qb + (size_t)z * 2097152 + (size_t)by * 128 * 1024;
    const unsigned short* B = Kb + (size_t)z * 2097152 + (size_t)bx * 128 * 1024;
    floatx16 acc[2][2];
#pragma unroll
    for (int a = 0; a < 2; ++a)
#pragma unroll
        for (int bj = 0; bj < 2; ++bj)
#pragma unroll
            for (int r = 0; r < 16; ++r) acc[a][bj][r] = 0.f;

    gemm_core(A, 1024, B, 1024, 1024, As, Bs, acc);

    const int wave = threadIdx.x >> 6, lane = threadIdx.x & 63;
    const int kg = lane >> 5;
    unsigned short* C = Sb + (size_t)z * 4194304;
    float* lz = l + z * 2048;
    const int cm = by * 128 + (wave >> 1) * 64;
    const int cn = bx * 128 + (wave & 1) * 64 + (lane & 31);
#pragma unroll
    for (int mt = 0; mt < 2; ++mt)
#pragma unroll
        for (int r = 0; r < 16; ++r) {
            const int row = cm + mt * 32 + EPI_ROW(r, kg);
            const float e0 = __expf(acc[mt][0][r] * 0.03125f);
            const float e1 = __expf(acc[mt][1][r] * 0.03125f);
            C[(size_t)row * 2048 + cn] = f2bf(e0);
            C[(size_t)row * 2048 + cn + 32] = f2bf(e1);
            float s = e0 + e1;
            s += __shfl_xor(s, 1);  s += __shfl_xor(s, 2);
            s += __shfl_xor(s, 4);  s += __shfl_xor(s, 8);
            s += __shfl_xor(s, 16);
            if ((lane & 31) == (mt * 16 + r)) atomicAdd(&lz[row], s);
        }
}

// ============ out = (P_unnorm @ Vt^T) / l[row] (fp32 out) ============
// (R0/R6-verified body)
__global__ __launch_bounds__(256, 4) void pv_kernel(
    const unsigned short* __restrict__ Sb, const unsigned short* __restrict__ Vt,
    const float* __restrict__ l, float* __restrict__ out) {
    __shared__ unsigned short As[128 * 64];
    __shared__ unsigned short Bs[128 * 64];
    const int i = blockIdx.x;                    // 0..511
    const int z = (i >> 1) & 3;
    const int slot = i >> 3;
    const int by = (i & 1) + 2 * (slot & 7);
    const int bx = slot >> 3;
    const unsigned short* A = Sb + (size_t)z * 4194304 + (size_t)by * 128 * 2048;
    const unsigned short* B = Vt + (size_t)z * 2097152 + (size_t)bx * 128 * 2048;
    floatx16 acc[2][2];
#pragma unroll
    for (int a = 0; a < 2; ++a)
#pragma unroll
        for (int bj = 0; bj < 2; ++bj)
#pragma unroll
            for (int r = 0; r < 16; ++r) acc[a][bj][r] = 0.f;

    gemm_core(A, 2048, B, 2048, 2048, As, Bs, acc);

    const int wave = threadIdx.x >> 6, lane = threadIdx.x & 63;
    const int kg = lane >> 5;
    float* C = out + (size_t)z * 2097152;
    const float* lz = l + z * 2048;
    const int cm = by * 128 + (wave >> 1) * 64;
    const int cn = bx * 128 + (wave & 1) * 64 + (lane & 31);
#pragma unroll
    for (int mt = 0; mt < 2; ++mt)
#pragma unroll
        for (int r = 0; r < 16; ++r) {
            const int row = cm + mt * 32 + EPI_ROW(r, kg);
            const float inv = 1.0f / lz[row];
            C[(size_t)row * 1024 + cn] = acc[mt][0][r] * inv;
            C[(size_t)row * 1024 + cn + 32] = acc[mt][1][r] * inv;
        }
}

extern "C" void kernel_launch(void* const* d_in, const int* in_sizes, int n_in,
                              void* d_out, int out_size, void* d_ws, size_t ws_size,
                              hipStream_t stream) {
    const float* x   = (const float*)d_in[0];
    const float* ctx = (const float*)d_in[1];
    const float* Wq  = (const float*)d_in[2];
    const float* bq  = (const float*)d_in[3];
    const float* Wk  = (const float*)d_in[4];
    const float* bk  = (const float*)d_in[5];
    const float* Wv  = (const float*)d_in[6];
    const float* bv  = (const float*)d_in[7];
    float* out = (float*)d_out;

    const size_t MB = 1024 * 1024;
    char* ws = (char*)d_ws;
    unsigned short* xb   = (unsigned short*)(ws + 0 * MB);
    unsigned short* cb   = (unsigned short*)(ws + 16 * MB);
    unsigned short* Qb   = (unsigned short*)(ws + 32 * MB);
    unsigned short* Kb   = (unsigned short*)(ws + 48 * MB);
    unsigned short* Vt   = (unsigned short*)(ws + 64 * MB);
    unsigned short* Wt0  = (unsigned short*)(ws + 80 * MB);
    unsigned short* WtKV = (unsigned short*)(ws + 82 * MB);
    unsigned short* Sb   = (unsigned short*)(ws + 86 * MB);
    float*          lrow = (float*)(ws + 118 * MB);   // 8192 fp32 row sums

    prep_kernel<<<16384 + 3072 + 8, 256, 0, stream>>>(
        x, ctx, Wq, Wk, Wv, xb, cb, Wt0, WtKV, lrow);
    qkv_kernel<<<1536, 256, 0, stream>>>(xb, cb, Wt0, WtKV, bq, bk, bv, Qb, Kb, Vt);
    qkt_kernel<<<1024, 256, 0, stream>>>(Qb, Kb, Sb, lrow);
    pv_kernel<<<512, 256, 0, stream>>>(Sb, Vt, lrow, out);
}

// Round 12
// 276.206 us; speedup vs baseline: 1.1089x; 1.0133x over previous
//
#include <hip/hip_runtime.h>
#include <cstdint>
#include <cstddef>

typedef __attribute__((ext_vector_type(8))) short short8;
typedef __attribute__((ext_vector_type(16))) float floatx16;

__device__ __forceinline__ unsigned short f2bf(float f) {
    union { float f; unsigned int u; } v; v.f = f;
    unsigned int r = v.u + 0x7fffu + ((v.u >> 16) & 1u);
    return (unsigned short)(r >> 16);
}

__device__ __forceinline__ void glds16(const void* g, void* l) {
    __builtin_amdgcn_global_load_lds(
        (const __attribute__((address_space(1))) void*)g,
        (__attribute__((address_space(3))) void*)l, 16, 0, 0);
}

// C/D layout (m74/m101, verified): col = lane&31, row = (r&3)+8*(r>>2)+4*kg
#define EPI_ROW(r, kg) (((r) & 3) + 8 * ((r) >> 2) + 4 * (kg))

// ============ 128x128 core, 2-barrier loop (measured 810 TF @ 4 blk/CU) ======
// Swizzle (verified: SQ_LDS_BANK_CONFLICT == 0): key(row)=(row^(row>>3))&7
__device__ __forceinline__ void gemm_core(
    const unsigned short* __restrict__ Ab, int ldA,
    const unsigned short* __restrict__ Bb, int ldB,
    int K,
    unsigned short* __restrict__ As, unsigned short* __restrict__ Bs,
    floatx16 (&acc)[2][2])
{
    const int tid = threadIdx.x;
    const int wave = tid >> 6, lane = tid & 63;

    const unsigned short* gA[4];
    const unsigned short* gB[4];
#pragma unroll
    for (int i = 0; i < 4; ++i) {
        const int c = i * 256 + tid;
        const int row = c >> 3;
        const int l = (c & 7) ^ ((row ^ (row >> 3)) & 7);
        gA[i] = Ab + (size_t)row * ldA + l * 8;
        gB[i] = Bb + (size_t)row * ldB + l * 8;
    }
    const int arow = (wave >> 1) * 64 + (lane & 31);
    const int brow = (wave & 1) * 64 + (lane & 31);
    const int kg = lane >> 5;
    const int sw = (lane & 7) ^ ((lane >> 3) & 3);
    const unsigned short* pa = As + arow * 64;
    const unsigned short* pb = Bs + brow * 64;

    for (int k0 = 0; k0 < K; k0 += 64) {
#pragma unroll
        for (int i = 0; i < 4; ++i)
            glds16(gA[i] + k0, As + (size_t)(i * 256 + wave * 64) * 8);
#pragma unroll
        for (int i = 0; i < 4; ++i)
            glds16(gB[i] + k0, Bs + (size_t)(i * 256 + wave * 64) * 8);
        __syncthreads();
#pragma unroll
        for (int s = 0; s < 4; ++s) {
            const int o0 = ((2 * s + kg) ^ sw) * 8;
            const int o1 = o0 ^ 32;
            short8 a0 = *(const short8*)(pa + o0);
            short8 a1 = *(const short8*)(pa + 32 * 64 + o1);
            short8 b0 = *(const short8*)(pb + o0);
            short8 b1 = *(const short8*)(pb + 32 * 64 + o1);
            acc[0][0] = __builtin_amdgcn_mfma_f32_32x32x16_bf16(a0, b0, acc[0][0], 0, 0, 0);
            acc[0][1] = __builtin_amdgcn_mfma_f32_32x32x16_bf16(a0, b1, acc[0][1], 0, 0, 0);
            acc[1][0] = __builtin_amdgcn_mfma_f32_32x32x16_bf16(a1, b0, acc[1][0], 0, 0, 0);
            acc[1][1] = __builtin_amdgcn_mfma_f32_32x32x16_bf16(a1, b1, acc[1][1], 0, 0, 0);
        }
        __syncthreads();
    }
}

// ====== prep: fp32->bf16 converts + weight transpose-converts + lrow zero ====
__global__ __launch_bounds__(256) void prep_kernel(
    const float* __restrict__ x, const float* __restrict__ ctx,
    const float* __restrict__ Wq, const float* __restrict__ Wk, const float* __restrict__ Wv,
    unsigned short* __restrict__ xb, unsigned short* __restrict__ cb,
    unsigned short* __restrict__ Wt0, unsigned short* __restrict__ WtKV,
    float* __restrict__ lrow) {
    const int b = blockIdx.x;
    if (b < 16384) {
        int i = b * 256 + threadIdx.x;
        const float* in; unsigned short* out; int j;
        if (i < 2097152) { in = x; out = xb; j = i; }
        else { in = ctx; out = cb; j = i - 2097152; }
        float4 v = reinterpret_cast<const float4*>(in)[j];
        ushort4 o;
        o.x = f2bf(v.x); o.y = f2bf(v.y); o.z = f2bf(v.z); o.w = f2bf(v.w);
        reinterpret_cast<ushort4*>(out)[j] = o;
    } else if (b < 19456) {
        // weight transpose, widened: float4 loads, ushort4 stores
        __shared__ float tile[32][33];
        const int z = b - 16384;
        const int w = z >> 10, t = z & 1023;
        const float* in = (w == 0) ? Wq : (w == 1) ? Wk : Wv;
        unsigned short* out = (w == 0) ? Wt0 : (w == 1) ? WtKV : (WtKV + 1024 * 1024);
        const int c0 = (t & 31) * 32, r0 = (t >> 5) * 32;
        const int tq = threadIdx.x & 7, tr = threadIdx.x >> 3;   // 8 x 32
        float4 v = *reinterpret_cast<const float4*>(&in[(size_t)(r0 + tr) * 1024 + c0 + tq * 4]);
        tile[tr][tq * 4 + 0] = v.x; tile[tr][tq * 4 + 1] = v.y;
        tile[tr][tq * 4 + 2] = v.z; tile[tr][tq * 4 + 3] = v.w;
        __syncthreads();
        ushort4 u;
        u.x = f2bf(tile[tq * 4 + 0][tr]);
        u.y = f2bf(tile[tq * 4 + 1][tr]);
        u.z = f2bf(tile[tq * 4 + 2][tr]);
        u.w = f2bf(tile[tq * 4 + 3][tr]);
        *reinterpret_cast<ushort4*>(&out[(size_t)(c0 + tr) * 1024 + r0 + tq * 4]) = u;
    } else {
        // zero lrow: 8192 floats = 2048 float4 over 8 blocks x 256 threads
        const int i = (b - 19456) * 256 + threadIdx.x;
        reinterpret_cast<float4*>(lrow)[i] = float4{0.f, 0.f, 0.f, 0.f};
    }
}

// ============ mega QKV: 1536 blocks of 128x128; Q (512) + KV (1024) ==========
// (R0/R6/R8-verified: ~66 us nominal, MfmaUtil 33-34%, FETCH ~52 MB.
//  Do NOT restructure: dispatch-order L2 locality is the load-bearing element —
//  persistent 2-tile loop (R9) and stripe-major orders (R7) both blow up FETCH.)
__global__ __launch_bounds__(256, 4) void qkv_kernel(
    const unsigned short* __restrict__ xb, const unsigned short* __restrict__ cb,
    const unsigned short* __restrict__ WtQ, const unsigned short* __restrict__ WtKV,
    const float* __restrict__ bq, const float* __restrict__ bk, const float* __restrict__ bv,
    unsigned short* __restrict__ Qb, unsigned short* __restrict__ Kb,
    unsigned short* __restrict__ Vt) {
    __shared__ unsigned short As[128 * 64];
    __shared__ unsigned short Bs[128 * 64];
    const int i = blockIdx.x;
    const bool isQ = i < 512;
    int by, bxcol;
    const unsigned short *A, *B;
    if (isQ) {
        const int slot = i >> 3;
        by = (i & 7) + 8 * (slot & 7);
        const int bx = slot >> 3; bxcol = bx * 128;
        A = xb + (size_t)by * 128 * 1024;
        B = WtQ + (size_t)bx * 128 * 1024;
    } else {
        const int j = i - 512;
        const int slot = j >> 3;
        by = (j & 7) + 8 * (slot & 7);
        const int bx = slot >> 3; bxcol = bx * 128;
        A = cb + (size_t)by * 128 * 1024;
        B = WtKV + (size_t)bx * 128 * 1024;
    }
    floatx16 acc[2][2];
#pragma unroll
    for (int a = 0; a < 2; ++a)
#pragma unroll
        for (int bj = 0; bj < 2; ++bj)
#pragma unroll
            for (int r = 0; r < 16; ++r) acc[a][bj][r] = 0.f;

    gemm_core(A, 1024, B, 1024, 1024, As, Bs, acc);

    const int wave = threadIdx.x >> 6, lane = threadIdx.x & 63;
    const int kg = lane >> 5;
    const int cm = by * 128 + (wave >> 1) * 64;
    const int cn = bxcol + (wave & 1) * 64 + (lane & 31);
    if (isQ || bxcol < 1024) {
        unsigned short* O = isQ ? Qb : Kb;
        const float* bias = isQ ? bq : bk;
#pragma unroll
        for (int nt = 0; nt < 2; ++nt) {
            const int col = cn + nt * 32;
            const float bvv = bias[col];
#pragma unroll
            for (int mt = 0; mt < 2; ++mt)
#pragma unroll
                for (int r = 0; r < 16; ++r) {
                    const int row = cm + mt * 32 + EPI_ROW(r, kg);
                    O[(size_t)row * 1024 + col] = f2bf(acc[mt][nt][r] + bvv);
                }
        }
    } else {
        // V half -> transposed write: Vt[b][colv][q]; 4 consecutive q per reg-quad
#pragma unroll
        for (int nt = 0; nt < 2; ++nt) {
            const int colv = cn + nt * 32 - 1024;
            const float bvv = bv[colv];
#pragma unroll
            for (int mt = 0; mt < 2; ++mt) {
                const int rowg = cm + mt * 32 + 4 * kg;
                const int b = rowg >> 11, qb = rowg & 2047;
#pragma unroll
                for (int g = 0; g < 4; ++g) {
                    const int q = qb + 8 * g;
                    ushort4 u;
                    u.x = f2bf(acc[mt][nt][g * 4 + 0] + bvv);
                    u.y = f2bf(acc[mt][nt][g * 4 + 1] + bvv);
                    u.z = f2bf(acc[mt][nt][g * 4 + 2] + bvv);
                    u.w = f2bf(acc[mt][nt][g * 4 + 3] + bvv);
                    *reinterpret_cast<ushort4*>(Vt + (size_t)b * 2097152 + (size_t)colv * 2048 + q) = u;
                }
            }
        }
    }
}

// ============ P_unnorm = exp(Q K^T * scale); row sums -> l via atomics ========
// Epilogue v2: recursive-halving reduce-scatter — all 16 row-sums per mt in
// 16 shfl (vs 80), all indices compile-time (no scratch), 16 concurrent
// atomics to distinct rows (2 cache lines).
__global__ __launch_bounds__(256, 4) void qkt_kernel(
    const unsigned short* __restrict__ Qb, const unsigned short* __restrict__ Kb,
    unsigned short* __restrict__ Sb, float* __restrict__ l) {
    __shared__ unsigned short As[128 * 64];
    __shared__ unsigned short Bs[128 * 64];
    const int i = blockIdx.x;                    // 0..1023
    const int z = (i >> 1) & 3;
    const int slot = i >> 3;
    const int by = (i & 1) + 2 * (slot & 7);
    const int bx = slot >> 3;
    const unsigned short* A = Qb + (size_t)z * 2097152 + (size_t)by * 128 * 1024;
    const unsigned short* B = Kb + (size_t)z * 2097152 + (size_t)bx * 128 * 1024;
    floatx16 acc[2][2];
#pragma unroll
    for (int a = 0; a < 2; ++a)
#pragma unroll
        for (int bj = 0; bj < 2; ++bj)
#pragma unroll
            for (int r = 0; r < 16; ++r) acc[a][bj][r] = 0.f;

    gemm_core(A, 1024, B, 1024, 1024, As, Bs, acc);

    const int wave = threadIdx.x >> 6, lane = threadIdx.x & 63;
    const int kg = lane >> 5;
    const int l31 = lane & 31;
    unsigned short* C = Sb + (size_t)z * 4194304;
    float* lz = l + z * 2048;
    const int cm = by * 128 + (wave >> 1) * 64;
    const int cn = bx * 128 + (wave & 1) * 64 + l31;
#pragma unroll
    for (int mt = 0; mt < 2; ++mt) {
        float sv[16];
#pragma unroll
        for (int r = 0; r < 16; ++r) {
            const int row = cm + mt * 32 + EPI_ROW(r, kg);
            const float e0 = __expf(acc[mt][0][r] * 0.03125f);
            const float e1 = __expf(acc[mt][1][r] * 0.03125f);
            C[(size_t)row * 2048 + cn] = f2bf(e0);
            C[(size_t)row * 2048 + cn + 32] = f2bf(e1);
            sv[r] = e0 + e1;
        }
        // reduce-scatter over 16 lanes (masks 8/4/2/1, compile-time indices),
        // then mask-16 combine: lane ends with full 32-lane sum for r = l31&15.
        float t8[8];
#pragma unroll
        for (int p = 0; p < 8; ++p) {
            const float give = (l31 & 8) ? sv[p] : sv[p + 8];
            const float keep = (l31 & 8) ? sv[p + 8] : sv[p];
            t8[p] = keep + __shfl_xor(give, 8);
        }
        float t4[4];
#pragma unroll
        for (int p = 0; p < 4; ++p) {
            const float give = (l31 & 4) ? t8[p] : t8[p + 4];
            const float keep = (l31 & 4) ? t8[p + 4] : t8[p];
            t4[p] = keep + __shfl_xor(give, 4);
        }
        float t2[2];
#pragma unroll
        for (int p = 0; p < 2; ++p) {
            const float give = (l31 & 2) ? t4[p] : t4[p + 2];
            const float keep = (l31 & 2) ? t4[p + 2] : t4[p];
            t2[p] = keep + __shfl_xor(give, 2);
        }
        {
            const float give = (l31 & 1) ? t2[0] : t2[1];
            const float keep = (l31 & 1) ? t2[1] : t2[0];
            const float t1 = keep + __shfl_xor(give, 1);
            const float tot = t1 + __shfl_xor(t1, 16);
            if (l31 < 16) {
                const int row = cm + mt * 32 + EPI_ROW(l31, kg);
                atomicAdd(&lz[row], tot);
            }
        }
    }
}

// ============ out = (P_unnorm @ Vt^T) / l[row] (fp32 out) ============
// (R0/R6-verified body)
__global__ __launch_bounds__(256, 4) void pv_kernel(
    const unsigned short* __restrict__ Sb, const unsigned short* __restrict__ Vt,
    const float* __restrict__ l, float* __restrict__ out) {
    __shared__ unsigned short As[128 * 64];
    __shared__ unsigned short Bs[128 * 64];
    const int i = blockIdx.x;                    // 0..511
    const int z = (i >> 1) & 3;
    const int slot = i >> 3;
    const int by = (i & 1) + 2 * (slot & 7);
    const int bx = slot >> 3;
    const unsigned short* A = Sb + (size_t)z * 4194304 + (size_t)by * 128 * 2048;
    const unsigned short* B = Vt + (size_t)z * 2097152 + (size_t)bx * 128 * 2048;
    floatx16 acc[2][2];
#pragma unroll
    for (int a = 0; a < 2; ++a)
#pragma unroll
        for (int bj = 0; bj < 2; ++bj)
#pragma unroll
            for (int r = 0; r < 16; ++r) acc[a][bj][r] = 0.f;

    gemm_core(A, 2048, B, 2048, 2048, As, Bs, acc);

    const int wave = threadIdx.x >> 6, lane = threadIdx.x & 63;
    const int kg = lane >> 5;
    float* C = out + (size_t)z * 2097152;
    const float* lz = l + z * 2048;
    const int cm = by * 128 + (wave >> 1) * 64;
    const int cn = bx * 128 + (wave & 1) * 64 + (lane & 31);
#pragma unroll
    for (int mt = 0; mt < 2; ++mt)
#pragma unroll
        for (int r = 0; r < 16; ++r) {
            const int row = cm + mt * 32 + EPI_ROW(r, kg);
            const float inv = 1.0f / lz[row];
            C[(size_t)row * 1024 + cn] = acc[mt][0][r] * inv;
            C[(size_t)row * 1024 + cn + 32] = acc[mt][1][r] * inv;
        }
}

extern "C" void kernel_launch(void* const* d_in, const int* in_sizes, int n_in,
                              void* d_out, int out_size, void* d_ws, size_t ws_size,
                              hipStream_t stream) {
    const float* x   = (const float*)d_in[0];
    const float* ctx = (const float*)d_in[1];
    const float* Wq  = (const float*)d_in[2];
    const float* bq  = (const float*)d_in[3];
    const float* Wk  = (const float*)d_in[4];
    const float* bk  = (const float*)d_in[5];
    const float* Wv  = (const float*)d_in[6];
    const float* bv  = (const float*)d_in[7];
    float* out = (float*)d_out;

    const size_t MB = 1024 * 1024;
    char* ws = (char*)d_ws;
    unsigned short* xb   = (unsigned short*)(ws + 0 * MB);
    unsigned short* cb   = (unsigned short*)(ws + 16 * MB);
    unsigned short* Qb   = (unsigned short*)(ws + 32 * MB);
    unsigned short* Kb   = (unsigned short*)(ws + 48 * MB);
    unsigned short* Vt   = (unsigned short*)(ws + 64 * MB);
    unsigned short* Wt0  = (unsigned short*)(ws + 80 * MB);
    unsigned short* WtKV = (unsigned short*)(ws + 82 * MB);
    unsigned short* Sb   = (unsigned short*)(ws + 86 * MB);
    float*          lrow = (float*)(ws + 118 * MB);   // 8192 fp32 row sums

    prep_kernel<<<16384 + 3072 + 8, 256, 0, stream>>>(
        x, ctx, Wq, Wk, Wv, xb, cb, Wt0, WtKV, lrow);
    qkv_kernel<<<1536, 256, 0, stream>>>(xb, cb, Wt0, WtKV, bq, bk, bv, Qb, Kb, Vt);
    qkt_kernel<<<1024, 256, 0, stream>>>(Qb, Kb, Sb, lrow);
    pv_kernel<<<512, 256, 0, stream>>>(Sb, Vt, lrow, out);
}